// Round 9
// baseline (122.241 us; speedup 1.0000x reference)
//
#include <hip/hip_runtime.h>

// NODE ensemble forward, round 8 — R7 structure + honest 256-VGPR budget +
// REPS=4 self-resolving diagnostic.
// R7 audit: live set during chunks 0-3 is s1(32)+acc(48)+bh(24-48)+addr(~25)
// ~= 130-150 VGPRs — my "fits 128" claim was wrong; if the allocator chose
// 128 (as R5 proved it prefers), s1 spilled to scratch mid-GEMM.
// Fix: amdgpu_waves_per_eu(2,2) (free: 117KB LDS already pins 2 waves/EU)
// WITHOUT R6's ordered asm pins (the real R6 regression).
// REPS=4 idempotent loop: if the fix works, reps are ~6-8us and total ~30us;
// if it fails, the kernel exceeds the harness's ~40us fill dispatches and
// surfaces in the rocprof top-5 with full counters (VGPR/spill evidence).
//
// B=16384, D=512, T=64, DEPTH=6, NCOL=384.

#define DD     512
#define NCOL   384
#define NDEPTH 6
#define REPS   4
#define PKELT  (NCOL * DD)     // elements per pk copy (196608)
#define XSTR   522             // xs row stride (bf16): odd dword count -> <=2-way
#define PRSTR  392             // pr row stride (bf16)

typedef __bf16 bf16_t;
typedef __bf16 bf16x8 __attribute__((ext_vector_type(8)));
typedef __bf16 bf16x4 __attribute__((ext_vector_type(4)));
typedef float  f32x4  __attribute__((ext_vector_type(4)));

static __device__ __forceinline__ float b2f(unsigned int u16) {
  unsigned int t = u16 << 16;
  float f;
  __builtin_memcpy(&f, &t, 4);
  return f;
}

// pk[c][((cf*16 + ksg)*64 + lane)*8 + j] = fsel[cf*16+(lane&15)][ksg*32+(lane>>4)*8+j]
// replicated x8 (one copy per XCD's L2)
__global__ __launch_bounds__(256) void node_pack(const float* __restrict__ fsel,
                                                 bf16_t* __restrict__ pk)
{
  int tid  = blockIdx.x * 256 + threadIdx.x;   // 0..24575
  int lane = tid & 63;
  int ksg  = (tid >> 6) & 15;
  int cf   = tid >> 10;                        // 0..23
  int col  = cf * 16 + (lane & 15);
  int k    = ksg * 32 + (lane >> 4) * 8;
  float4 f0 = *reinterpret_cast<const float4*>(fsel + (size_t)col * DD + k);
  float4 f1 = *reinterpret_cast<const float4*>(fsel + (size_t)col * DD + k + 4);
  bf16x8 v;
  v[0] = (bf16_t)f0.x; v[1] = (bf16_t)f0.y; v[2] = (bf16_t)f0.z; v[3] = (bf16_t)f0.w;
  v[4] = (bf16_t)f1.x; v[5] = (bf16_t)f1.y; v[6] = (bf16_t)f1.z; v[7] = (bf16_t)f1.w;
  #pragma unroll
  for (int c = 0; c < 8; ++c)
    *reinterpret_cast<bf16x8*>(pk + (size_t)c * PKELT + (size_t)tid * 8) = v;
}

__global__ void __launch_bounds__(512) __attribute__((amdgpu_waves_per_eu(2, 2)))
node_fused(const float*  __restrict__ x,      // [B][512]
           const bf16_t* __restrict__ pk,     // packed B frags, x8 copies
           const float*  __restrict__ thr,    // [384]
           const float*  __restrict__ lw,     // [64][64]
           float*        __restrict__ out)    // [B]
{
  __shared__ bf16_t xs[64 * XSTR];     // 66816 B: full x block, bf16
  __shared__ bf16_t pr[64 * PRSTR];    // 50176 B: sigmoid probs

  const int tid  = threadIdx.x;
  const int lane = tid & 63;
  const int wv   = tid >> 6;           // 0..7; wave owns cols wv*48..+47
  const int rowblk = blockIdx.x * 64;
  const int c   = lane & 15;
  const int kg  = lane >> 4;
  const bf16_t* pkc = pk + (size_t)(blockIdx.x & 7) * PKELT;

  float th[3];
  #pragma unroll
  for (int f = 0; f < 3; ++f) th[f] = thr[wv * 48 + f * 16 + c];

  #pragma unroll 1
  for (int rep = 0; rep < REPS; ++rep) {

    // ---- issue both x half-loads up front ----
    float4 s0[8], s1[8];
    #pragma unroll
    for (int i = 0; i < 8; ++i) {
      int idx = i * 512 + tid, e = idx << 2, r = e >> 8, k = e & 255;
      s0[i] = *reinterpret_cast<const float4*>(x + (size_t)(rowblk + r) * DD + k);
    }
    #pragma unroll
    for (int i = 0; i < 8; ++i) {
      int idx = i * 512 + tid, e = idx << 2, r = e >> 8, k = e & 255;
      s1[i] = *reinterpret_cast<const float4*>(x + (size_t)(rowblk + r) * DD + 256 + k);
    }
    // write half 0 (waits s0 only; s1 stays in flight)
    #pragma unroll
    for (int i = 0; i < 8; ++i) {
      int idx = i * 512 + tid, e = idx << 2, r = e >> 8, k = e & 255;
      bf16x4 v;
      v[0] = (bf16_t)s0[i].x; v[1] = (bf16_t)s0[i].y;
      v[2] = (bf16_t)s0[i].z; v[3] = (bf16_t)s0[i].w;
      *reinterpret_cast<bf16x4*>(&xs[r * XSTR + k]) = v;
    }
    asm volatile("s_waitcnt lgkmcnt(0)" ::: "memory");
    __builtin_amdgcn_s_barrier();        // xs half-0 ready

    f32x4 acc[4][3];
    #pragma unroll
    for (int t = 0; t < 4; ++t)
      #pragma unroll
      for (int f = 0; f < 3; ++f) acc[t][f] = (f32x4){0.f, 0.f, 0.f, 0.f};

    // ---- GEMM: 8 K-chunks of 64; chunks 0-3 = half 0, 4-7 = half 1 ----
    #pragma unroll
    for (int ch = 0; ch < 8; ++ch) {
      if (ch == 4) {
        #pragma unroll
        for (int i = 0; i < 8; ++i) {
          int idx = i * 512 + tid, e = idx << 2, r = e >> 8, k = e & 255;
          bf16x4 v;
          v[0] = (bf16_t)s1[i].x; v[1] = (bf16_t)s1[i].y;
          v[2] = (bf16_t)s1[i].z; v[3] = (bf16_t)s1[i].w;
          *reinterpret_cast<bf16x4*>(&xs[r * XSTR + 256 + k]) = v;
        }
        asm volatile("s_waitcnt lgkmcnt(0)" ::: "memory");
        __builtin_amdgcn_s_barrier();    // xs half-1 ready
      }

      bf16x8 bh[3][2];
      #pragma unroll
      for (int f = 0; f < 3; ++f)
        #pragma unroll
        for (int ks = 0; ks < 2; ++ks)
          bh[f][ks] = *reinterpret_cast<const bf16x8*>(
              pkc + ((size_t)(((wv * 3 + f) * 16 + ch * 2 + ks) * 64) + lane) * 8);

      #pragma unroll
      for (int t = 0; t < 4; ++t) {
        #pragma unroll
        for (int ks = 0; ks < 2; ++ks) {
          bf16x8 a = *reinterpret_cast<const bf16x8*>(
              &xs[(t * 16 + c) * XSTR + ch * 64 + ks * 32 + kg * 8]);
          acc[t][0] = __builtin_amdgcn_mfma_f32_16x16x32_bf16(a, bh[0][ks], acc[t][0], 0, 0, 0);
          acc[t][1] = __builtin_amdgcn_mfma_f32_16x16x32_bf16(a, bh[1][ks], acc[t][1], 0, 0, 0);
          acc[t][2] = __builtin_amdgcn_mfma_f32_16x16x32_bf16(a, bh[2][ks], acc[t][2], 0, 0, 0);
        }
      }
    }

    // ---- epilogue: sigmoid -> pr. D: row = t*16 + kg*4 + r, col = wv*48+f*16+c
    #pragma unroll
    for (int t = 0; t < 4; ++t) {
      #pragma unroll
      for (int f = 0; f < 3; ++f) {
        const int col = wv * 48 + f * 16 + c;
        #pragma unroll
        for (int r = 0; r < 4; ++r) {
          const int row = t * 16 + kg * 4 + r;
          float z = acc[t][f][r] - th[f];
          float p = 1.0f / (1.0f + __expf(-z));
          pr[row * PRSTR + col] = (bf16_t)p;
        }
      }
    }
    asm volatile("s_waitcnt lgkmcnt(0)" ::: "memory");
    __builtin_amdgcn_s_barrier();        // pr complete

    // ---- fold: lane = tree; two 32-leaf half-trees ----
    float p0v[8], hv0[8], hv1[8];
    #pragma unroll
    for (int half = 0; half < 2; ++half) {
      float wch[32];
      #pragma unroll
      for (int j = 0; j < 8; ++j) {
        float4 f4 = *reinterpret_cast<const float4*>(lw + (size_t)lane * 64 + half * 32 + j * 4);
        wch[4*j] = f4.x; wch[4*j+1] = f4.y; wch[4*j+2] = f4.z; wch[4*j+3] = f4.w;
      }
      #pragma unroll
      for (int rr = 0; rr < 8; ++rr) {
        const int row = wv * 8 + rr;
        const unsigned int* prow =
            reinterpret_cast<const unsigned int*>(&pr[row * PRSTR]) + lane * 3;
        unsigned int d0 = prow[0], d1 = prow[1], d2 = prow[2];
        float p1 = b2f(d0 >> 16);
        float p2 = b2f(d1 & 0xffffu), p3 = b2f(d1 >> 16);
        float p4 = b2f(d2 & 0xffffu), p5 = b2f(d2 >> 16);
        if (half == 0) p0v[rr] = b2f(d0 & 0xffffu);

        float v[16];
        #pragma unroll
        for (int j = 0; j < 16; ++j) v[j] = fmaf(p5, wch[2*j] - wch[2*j+1], wch[2*j+1]);
        #pragma unroll
        for (int j = 0; j < 8;  ++j) v[j] = fmaf(p4, v[2*j] - v[2*j+1], v[2*j+1]);
        #pragma unroll
        for (int j = 0; j < 4;  ++j) v[j] = fmaf(p3, v[2*j] - v[2*j+1], v[2*j+1]);
        #pragma unroll
        for (int j = 0; j < 2;  ++j) v[j] = fmaf(p2, v[2*j] - v[2*j+1], v[2*j+1]);
        float s = fmaf(p1, v[0] - v[1], v[1]);
        if (half == 0) hv0[rr] = s; else hv1[rr] = s;
      }
    }

    float tvv[8];
    #pragma unroll
    for (int rr = 0; rr < 8; ++rr)
      tvv[rr] = fmaf(p0v[rr], hv0[rr] - hv1[rr], hv1[rr]);

    #pragma unroll
    for (int off = 32; off; off >>= 1) {
      #pragma unroll
      for (int rr = 0; rr < 8; ++rr) tvv[rr] += __shfl_xor(tvv[rr], off, 64);
    }
    if (lane == 0) {
      #pragma unroll
      for (int rr = 0; rr < 8; ++rr) out[rowblk + wv * 8 + rr] = tvv[rr];
    }

    __builtin_amdgcn_s_barrier();        // protect pr/xs for next rep
  }
}

extern "C" void kernel_launch(void* const* d_in, const int* in_sizes, int n_in,
                              void* d_out, int out_size, void* d_ws, size_t ws_size,
                              hipStream_t stream) {
  const float* x    = (const float*)d_in[0];
  const float* fsel = (const float*)d_in[1];
  const float* thr  = (const float*)d_in[2];
  const float* lw   = (const float*)d_in[3];
  float* out = (float*)d_out;

  bf16_t* pk = (bf16_t*)d_ws;                 // 8 x 393216 B

  const int B = in_sizes[0] / DD;             // 16384

  node_pack<<<dim3(96), dim3(256), 0, stream>>>(fsel, pk);
  node_fused<<<dim3(B / 64), dim3(512), 0, stream>>>(x, pk, thr, lw, out);
}

// Round 10
// 29.714 us; speedup vs baseline: 4.1139x; 4.1139x over previous
//
#include <hip/hip_runtime.h>

// NODE ensemble forward, round 9 — compose the two MEASURED-good phases.
// R5 evidence: R4-structure gemm pass = 6.9us/rep at VGPR=128 (no spill);
// fold with w[64]+v[32] = 15.7us (spill). R8 counters: waves_per_eu(2,2)
// ignored (VGPR stays 128), s0/s1-held-across-GEMM spills 10MB/rep.
// => gemm phase: R5's exact structure (st[4] tile staging, breg[3][16],
//    xf frag-layout 16KB, 4 tiles, lgkmcnt-only barriers).
// => fold phase: R7's two 32-leaf half-trees (peak live ~92 regs, no spill).
// pr stride 392 (2-way write aliasing = free). No attributes, no asm pins.
//
// B=16384, D=512, T=64, DEPTH=6, NCOL=384.

#define DD     512
#define NCOL   384
#define NDEPTH 6
#define PKELT  (NCOL * DD)     // elements per pk copy (196608)
#define PRSTR  392             // pr row stride (bf16)

typedef __bf16 bf16_t;
typedef __bf16 bf16x8 __attribute__((ext_vector_type(8)));
typedef float  f32x4  __attribute__((ext_vector_type(4)));

static __device__ __forceinline__ float b2f(unsigned int u16) {
  unsigned int t = u16 << 16;
  float f;
  __builtin_memcpy(&f, &t, 4);
  return f;
}

// pk[c][((cf*16 + ksg)*64 + lane)*8 + j] = fsel[cf*16+(lane&15)][ksg*32+(lane>>4)*8+j]
// replicated x8 (one copy per XCD's L2)
__global__ __launch_bounds__(256) void node_pack(const float* __restrict__ fsel,
                                                 bf16_t* __restrict__ pk)
{
  int tid  = blockIdx.x * 256 + threadIdx.x;   // 0..24575
  int lane = tid & 63;
  int ksg  = (tid >> 6) & 15;
  int cf   = tid >> 10;                        // 0..23
  int col  = cf * 16 + (lane & 15);
  int k    = ksg * 32 + (lane >> 4) * 8;
  float4 f0 = *reinterpret_cast<const float4*>(fsel + (size_t)col * DD + k);
  float4 f1 = *reinterpret_cast<const float4*>(fsel + (size_t)col * DD + k + 4);
  bf16x8 v;
  v[0] = (bf16_t)f0.x; v[1] = (bf16_t)f0.y; v[2] = (bf16_t)f0.z; v[3] = (bf16_t)f0.w;
  v[4] = (bf16_t)f1.x; v[5] = (bf16_t)f1.y; v[6] = (bf16_t)f1.z; v[7] = (bf16_t)f1.w;
  #pragma unroll
  for (int c = 0; c < 8; ++c)
    *reinterpret_cast<bf16x8*>(pk + (size_t)c * PKELT + (size_t)tid * 8) = v;
}

__global__ __launch_bounds__(512, 2) void node_fused(
    const float*  __restrict__ x,      // [B][512]
    const bf16_t* __restrict__ pk,     // packed B frags, x8 copies
    const float*  __restrict__ thr,    // [384]
    const float*  __restrict__ lw,     // [64][64]
    float*        __restrict__ out)    // [B]
{
  // xf: 16-row x-tile in MFMA frag layout: xf[(ks*64+lane)*8 + j]
  __shared__ bf16_t xf[8192];          // 16 KiB
  __shared__ bf16_t pr[64 * PRSTR];    // 50176 B: sigmoid probs

  const int tid  = threadIdx.x;
  const int lane = tid & 63;
  const int wv   = tid >> 6;           // 0..7; wave owns cols wv*48..+47
  const int rowblk = blockIdx.x * 64;
  const int srow = lane & 15;
  const int skg  = lane >> 4;
  const bf16_t* pkc = pk + (size_t)(blockIdx.x & 7) * PKELT;

  // ---- B fragments (the allocator keeps what fits; rest re-loads from
  //      the XCD-local L2 copy — this exact pattern measured 6.9us in R5) ----
  bf16x8 breg[3][16];
  #pragma unroll
  for (int f = 0; f < 3; ++f) {
    #pragma unroll
    for (int ks = 0; ks < 16; ++ks) {
      breg[f][ks] = *reinterpret_cast<const bf16x8*>(
          pkc + ((size_t)(((wv * 3 + f) * 16 + ks) * 64) + lane) * 8);
    }
  }

  float th[3];
  #pragma unroll
  for (int f = 0; f < 3; ++f) th[f] = thr[wv * 48 + f * 16 + (lane & 15)];

  float4 st[4];

  #define ISSUE_LOADS(t)                                                        \
    do {                                                                        \
      const float* base_ = x + (size_t)(rowblk + (t) * 16 + srow) * DD + skg*8; \
      st[0] = *reinterpret_cast<const float4*>(base_ + wv * 32);                \
      st[1] = *reinterpret_cast<const float4*>(base_ + wv * 32 + 4);            \
      st[2] = *reinterpret_cast<const float4*>(base_ + (wv + 8) * 32);          \
      st[3] = *reinterpret_cast<const float4*>(base_ + (wv + 8) * 32 + 4);      \
    } while (0)

  #define WRITE_LDS()                                                           \
    do {                                                                        \
      bf16x8 v0_, v1_;                                                          \
      v0_[0]=(bf16_t)st[0].x; v0_[1]=(bf16_t)st[0].y;                           \
      v0_[2]=(bf16_t)st[0].z; v0_[3]=(bf16_t)st[0].w;                           \
      v0_[4]=(bf16_t)st[1].x; v0_[5]=(bf16_t)st[1].y;                           \
      v0_[6]=(bf16_t)st[1].z; v0_[7]=(bf16_t)st[1].w;                           \
      v1_[0]=(bf16_t)st[2].x; v1_[1]=(bf16_t)st[2].y;                           \
      v1_[2]=(bf16_t)st[2].z; v1_[3]=(bf16_t)st[2].w;                           \
      v1_[4]=(bf16_t)st[3].x; v1_[5]=(bf16_t)st[3].y;                           \
      v1_[6]=(bf16_t)st[3].z; v1_[7]=(bf16_t)st[3].w;                           \
      *reinterpret_cast<bf16x8*>(&xf[(wv * 64 + lane) * 8])       = v0_;        \
      *reinterpret_cast<bf16x8*>(&xf[((wv + 8) * 64 + lane) * 8]) = v1_;        \
    } while (0)

  ISSUE_LOADS(0);

  // ---- 4 tiles of 16 rows: MFMA + sigmoid -> pr (LDS) ----
  #pragma unroll
  for (int t = 0; t < 4; ++t) {
    WRITE_LDS();                       // vmcnt wait via st reg deps
    if (t < 3) ISSUE_LOADS(t + 1);     // next tile's loads fly during MFMA
    asm volatile("s_waitcnt lgkmcnt(0)" ::: "memory");
    __builtin_amdgcn_s_barrier();      // xf ready for all waves

    f32x4 acc[3];
    #pragma unroll
    for (int f = 0; f < 3; ++f) acc[f] = (f32x4){0.f, 0.f, 0.f, 0.f};

    #pragma unroll
    for (int ks = 0; ks < 16; ++ks) {
      bf16x8 a = *reinterpret_cast<const bf16x8*>(&xf[(ks * 64 + lane) * 8]);
      acc[0] = __builtin_amdgcn_mfma_f32_16x16x32_bf16(a, breg[0][ks], acc[0], 0, 0, 0);
      acc[1] = __builtin_amdgcn_mfma_f32_16x16x32_bf16(a, breg[1][ks], acc[1], 0, 0, 0);
      acc[2] = __builtin_amdgcn_mfma_f32_16x16x32_bf16(a, breg[2][ks], acc[2], 0, 0, 0);
    }

    // sigmoid + store to pr. D: row=(lane>>4)*4+r, col=wv*48+f*16+(lane&15)
    #pragma unroll
    for (int f = 0; f < 3; ++f) {
      const int col = wv * 48 + f * 16 + (lane & 15);
      #pragma unroll
      for (int r = 0; r < 4; ++r) {
        const int row = t * 16 + (lane >> 4) * 4 + r;
        float z = acc[f][r] - th[f];
        float p = 1.0f / (1.0f + __expf(-z));
        pr[row * PRSTR + col] = (bf16_t)p;
      }
    }

    asm volatile("s_waitcnt lgkmcnt(0)" ::: "memory");
    __builtin_amdgcn_s_barrier();      // xf reads + pr writes done
  }
  #undef ISSUE_LOADS
  #undef WRITE_LDS

  // ---- fold: lane = tree; two 32-leaf half-trees (peak live ~92 regs) ----
  float p0v[8], hv0[8], hv1[8];
  #pragma unroll
  for (int half = 0; half < 2; ++half) {
    float wch[32];
    #pragma unroll
    for (int j = 0; j < 8; ++j) {
      float4 f4 = *reinterpret_cast<const float4*>(lw + (size_t)lane * 64 + half * 32 + j * 4);
      wch[4*j] = f4.x; wch[4*j+1] = f4.y; wch[4*j+2] = f4.z; wch[4*j+3] = f4.w;
    }
    #pragma unroll
    for (int rr = 0; rr < 8; ++rr) {
      const int row = wv * 8 + rr;
      const unsigned int* prow =
          reinterpret_cast<const unsigned int*>(&pr[row * PRSTR]) + lane * 3;
      unsigned int d0 = prow[0], d1 = prow[1], d2 = prow[2];
      float p1 = b2f(d0 >> 16);
      float p2 = b2f(d1 & 0xffffu), p3 = b2f(d1 >> 16);
      float p4 = b2f(d2 & 0xffffu), p5 = b2f(d2 >> 16);
      if (half == 0) p0v[rr] = b2f(d0 & 0xffffu);

      float v[16];
      #pragma unroll
      for (int j = 0; j < 16; ++j) v[j] = fmaf(p5, wch[2*j] - wch[2*j+1], wch[2*j+1]);
      #pragma unroll
      for (int j = 0; j < 8;  ++j) v[j] = fmaf(p4, v[2*j] - v[2*j+1], v[2*j+1]);
      #pragma unroll
      for (int j = 0; j < 4;  ++j) v[j] = fmaf(p3, v[2*j] - v[2*j+1], v[2*j+1]);
      #pragma unroll
      for (int j = 0; j < 2;  ++j) v[j] = fmaf(p2, v[2*j] - v[2*j+1], v[2*j+1]);
      float s = fmaf(p1, v[0] - v[1], v[1]);
      if (half == 0) hv0[rr] = s; else hv1[rr] = s;
    }
  }

  float tvv[8];
  #pragma unroll
  for (int rr = 0; rr < 8; ++rr)
    tvv[rr] = fmaf(p0v[rr], hv0[rr] - hv1[rr], hv1[rr]);

  // batched butterfly over 64 trees: 8 independent chains
  #pragma unroll
  for (int off = 32; off; off >>= 1) {
    #pragma unroll
    for (int rr = 0; rr < 8; ++rr) tvv[rr] += __shfl_xor(tvv[rr], off, 64);
  }
  if (lane == 0) {
    #pragma unroll
    for (int rr = 0; rr < 8; ++rr) out[rowblk + wv * 8 + rr] = tvv[rr];
  }
}

extern "C" void kernel_launch(void* const* d_in, const int* in_sizes, int n_in,
                              void* d_out, int out_size, void* d_ws, size_t ws_size,
                              hipStream_t stream) {
  const float* x    = (const float*)d_in[0];
  const float* fsel = (const float*)d_in[1];
  const float* thr  = (const float*)d_in[2];
  const float* lw   = (const float*)d_in[3];
  float* out = (float*)d_out;

  bf16_t* pk = (bf16_t*)d_ws;                 // 8 x 393216 B

  const int B = in_sizes[0] / DD;             // 16384

  node_pack<<<dim3(96), dim3(256), 0, stream>>>(fsel, pk);
  node_fused<<<dim3(B / 64), dim3(512), 0, stream>>>(x, pk, thr, lw, out);
}

// Round 11
// 27.275 us; speedup vs baseline: 4.4818x; 1.0894x over previous
//
#include <hip/hip_runtime.h>

// NODE ensemble forward, round 10 — R7 structure, pressure-engineered < 128 VGPR.
// Evidence base: R8 counters (VGPR pinned at 128, ~10MB/rep spill from s1-held-
// across-GEMM + hoisted B loads); R9 regression (breg[3][16] re-fetch at 128cap).
// Design: x staged in 8 chunks of 64 cols (stg[2][2]=16 regs, prefetch dist 3);
// B in bh[3][2]=24 regs prefetched 1 chunk ahead (counted vmcnt, never drained);
// one volatile pin per chunk anchors load issue points between barriers
// (prevents global hoisting WITHOUT R6's per-value serialization).
// Steady-state live ~110 regs; fold = half-trees (~92). No spill anywhere.
//
// B=16384, D=512, T=64, DEPTH=6, NCOL=384.

#define DD     512
#define NCOL   384
#define PKELT  (NCOL * DD)     // elements per pk copy (196608)
#define XSTR   522             // xs row stride (bf16)
#define PRSTR  392             // pr row stride (bf16)

typedef __bf16 bf16_t;
typedef __bf16 bf16x8 __attribute__((ext_vector_type(8)));
typedef __bf16 bf16x4 __attribute__((ext_vector_type(4)));
typedef float  f32x4  __attribute__((ext_vector_type(4)));

static __device__ __forceinline__ float b2f(unsigned int u16) {
  unsigned int t = u16 << 16;
  float f;
  __builtin_memcpy(&f, &t, 4);
  return f;
}

// pk[c][((cf*16 + ksg)*64 + lane)*8 + j] = fsel[cf*16+(lane&15)][ksg*32+(lane>>4)*8+j]
// replicated x8 (one copy per XCD's L2)
__global__ __launch_bounds__(256) void node_pack(const float* __restrict__ fsel,
                                                 bf16_t* __restrict__ pk)
{
  int tid  = blockIdx.x * 256 + threadIdx.x;   // 0..24575
  int lane = tid & 63;
  int ksg  = (tid >> 6) & 15;
  int cf   = tid >> 10;                        // 0..23
  int col  = cf * 16 + (lane & 15);
  int k    = ksg * 32 + (lane >> 4) * 8;
  float4 f0 = *reinterpret_cast<const float4*>(fsel + (size_t)col * DD + k);
  float4 f1 = *reinterpret_cast<const float4*>(fsel + (size_t)col * DD + k + 4);
  bf16x8 v;
  v[0] = (bf16_t)f0.x; v[1] = (bf16_t)f0.y; v[2] = (bf16_t)f0.z; v[3] = (bf16_t)f0.w;
  v[4] = (bf16_t)f1.x; v[5] = (bf16_t)f1.y; v[6] = (bf16_t)f1.z; v[7] = (bf16_t)f1.w;
  #pragma unroll
  for (int c = 0; c < 8; ++c)
    *reinterpret_cast<bf16x8*>(pk + (size_t)c * PKELT + (size_t)tid * 8) = v;
}

__global__ __launch_bounds__(512, 2) void node_fused(
    const float*  __restrict__ x,      // [B][512]
    const bf16_t* __restrict__ pk,     // packed B frags, x8 copies
    const float*  __restrict__ thr,    // [384]
    const float*  __restrict__ lw,     // [64][64]
    float*        __restrict__ out)    // [B]
{
  __shared__ bf16_t xs[64 * XSTR];     // 66816 B: full x block, bf16
  __shared__ bf16_t pr[64 * PRSTR];    // 50176 B: sigmoid probs

  const int tid  = threadIdx.x;
  const int lane = tid & 63;
  const int wv   = tid >> 6;           // 0..7; wave owns cols wv*48..+47
  const int rowblk = blockIdx.x * 64;
  const int c   = lane & 15;
  const int kg  = lane >> 4;

  // staging geometry: thread covers rows (tid>>4) and (tid>>4)+32,
  // cols (tid&15)*4 .. +3 of each 64-col chunk
  const float* xr0 = x + (size_t)(rowblk + (tid >> 4)) * DD + ((tid & 15) << 2);
  const float* xr1 = xr0 + (size_t)32 * DD;
  bf16_t* xw0 = &xs[(tid >> 4) * XSTR + ((tid & 15) << 2)];
  bf16_t* xw1 = &xs[((tid >> 4) + 32) * XSTR + ((tid & 15) << 2)];

  float th[3];
  #pragma unroll
  for (int f = 0; f < 3; ++f) th[f] = thr[wv * 48 + f * 16 + c];

  float4 stg[2][2];

  // issue x loads for chunk n (pinned base so the 16 loads can't all hoist)
  #define ISSUE(n, buf)                                                         \
    do {                                                                        \
      int off_ = (n) * 64;                                                      \
      asm volatile("" : "+v"(off_));                                            \
      stg[buf][0] = *reinterpret_cast<const float4*>(xr0 + off_);               \
      stg[buf][1] = *reinterpret_cast<const float4*>(xr1 + off_);               \
    } while (0)

  #define WRITE(n, buf)                                                         \
    do {                                                                        \
      bf16x4 v0_, v1_;                                                          \
      v0_[0]=(bf16_t)stg[buf][0].x; v0_[1]=(bf16_t)stg[buf][0].y;               \
      v0_[2]=(bf16_t)stg[buf][0].z; v0_[3]=(bf16_t)stg[buf][0].w;               \
      v1_[0]=(bf16_t)stg[buf][1].x; v1_[1]=(bf16_t)stg[buf][1].y;               \
      v1_[2]=(bf16_t)stg[buf][1].z; v1_[3]=(bf16_t)stg[buf][1].w;               \
      *reinterpret_cast<bf16x4*>(xw0 + (n) * 64) = v0_;                         \
      *reinterpret_cast<bf16x4*>(xw1 + (n) * 64) = v1_;                         \
    } while (0)

  // load bh for chunk n (pinned per-chunk base q_)
  bf16x8 bh[3][2];
  #define LOAD_BH(n)                                                            \
    do {                                                                        \
      const bf16_t* q_ = pk + (size_t)(blockIdx.x & 7) * PKELT +                \
                         (size_t)lane * 8 + (size_t)(n) * 1024 +                \
                         (size_t)wv * 3 * 8192;                                 \
      asm volatile("" : "+v"(q_));                                              \
      _Pragma("unroll")                                                         \
      for (int f_ = 0; f_ < 3; ++f_)                                            \
        _Pragma("unroll")                                                       \
        for (int ks_ = 0; ks_ < 2; ++ks_)                                       \
          bh[f_][ks_] = *reinterpret_cast<const bf16x8*>(                       \
              q_ + f_ * 8192 + ks_ * 512);                                      \
    } while (0)

  // ---- prologue: chunks 0,1,2 issued; chunk 0 written; bh(0) in flight ----
  ISSUE(0, 0);
  ISSUE(1, 1);
  WRITE(0, 0);                         // waits stg[0] loads only (counted vmcnt)
  ISSUE(2, 0);
  asm volatile("s_waitcnt lgkmcnt(0)" ::: "memory");
  __builtin_amdgcn_s_barrier();        // xs chunk 0 visible
  LOAD_BH(0);

  f32x4 acc[4][3];
  #pragma unroll
  for (int t = 0; t < 4; ++t)
    #pragma unroll
    for (int f = 0; f < 3; ++f) acc[t][f] = (f32x4){0.f, 0.f, 0.f, 0.f};

  // ---- 8-chunk pipelined GEMM ----
  #pragma unroll
  for (int ch = 0; ch < 8; ++ch) {
    // MFMA chunk ch (compiler waits bh via counted vmcnt, a via lgkmcnt)
    #pragma unroll
    for (int t = 0; t < 4; ++t) {
      #pragma unroll
      for (int ks = 0; ks < 2; ++ks) {
        bf16x8 a = *reinterpret_cast<const bf16x8*>(
            &xs[(t * 16 + c) * XSTR + ch * 64 + ks * 32 + kg * 8]);
        acc[t][0] = __builtin_amdgcn_mfma_f32_16x16x32_bf16(a, bh[0][ks], acc[t][0], 0, 0, 0);
        acc[t][1] = __builtin_amdgcn_mfma_f32_16x16x32_bf16(a, bh[1][ks], acc[t][1], 0, 0, 0);
        acc[t][2] = __builtin_amdgcn_mfma_f32_16x16x32_bf16(a, bh[2][ks], acc[t][2], 0, 0, 0);
      }
    }
    if (ch < 7) {
      LOAD_BH(ch + 1);                 // WAR on bh regs: safe, MFMAs issued
      WRITE(ch + 1, (ch + 1) & 1);     // counted vmcnt for that chunk's loads
      if (ch < 5) ISSUE(ch + 3, (ch + 1) & 1);
      asm volatile("s_waitcnt lgkmcnt(0)" ::: "memory");
      __builtin_amdgcn_s_barrier();    // xs chunk ch+1 visible
    }
  }
  #undef ISSUE
  #undef WRITE
  #undef LOAD_BH

  // ---- sigmoid -> pr. D: row = t*16 + kg*4 + r, col = wv*48 + f*16 + c ----
  #pragma unroll
  for (int t = 0; t < 4; ++t) {
    #pragma unroll
    for (int f = 0; f < 3; ++f) {
      const int col = wv * 48 + f * 16 + c;
      #pragma unroll
      for (int r = 0; r < 4; ++r) {
        const int row = t * 16 + kg * 4 + r;
        float z = acc[t][f][r] - th[f];
        float p = 1.0f / (1.0f + __expf(-z));
        pr[row * PRSTR + col] = (bf16_t)p;
      }
    }
  }
  asm volatile("s_waitcnt lgkmcnt(0)" ::: "memory");
  __builtin_amdgcn_s_barrier();        // pr complete

  // ---- fold: lane = tree; two 32-leaf half-trees (peak live ~92 regs) ----
  float p0v[8], hv0[8], hv1[8];
  #pragma unroll
  for (int half = 0; half < 2; ++half) {
    float wch[32];
    #pragma unroll
    for (int j = 0; j < 8; ++j) {
      float4 f4 = *reinterpret_cast<const float4*>(lw + (size_t)lane * 64 + half * 32 + j * 4);
      wch[4*j] = f4.x; wch[4*j+1] = f4.y; wch[4*j+2] = f4.z; wch[4*j+3] = f4.w;
    }
    #pragma unroll
    for (int rr = 0; rr < 8; ++rr) {
      const int row = wv * 8 + rr;
      const unsigned int* prow =
          reinterpret_cast<const unsigned int*>(&pr[row * PRSTR]) + lane * 3;
      unsigned int d0 = prow[0], d1 = prow[1], d2 = prow[2];
      float p1 = b2f(d0 >> 16);
      float p2 = b2f(d1 & 0xffffu), p3 = b2f(d1 >> 16);
      float p4 = b2f(d2 & 0xffffu), p5 = b2f(d2 >> 16);
      if (half == 0) p0v[rr] = b2f(d0 & 0xffffu);

      float v[16];
      #pragma unroll
      for (int j = 0; j < 16; ++j) v[j] = fmaf(p5, wch[2*j] - wch[2*j+1], wch[2*j+1]);
      #pragma unroll
      for (int j = 0; j < 8;  ++j) v[j] = fmaf(p4, v[2*j] - v[2*j+1], v[2*j+1]);
      #pragma unroll
      for (int j = 0; j < 4;  ++j) v[j] = fmaf(p3, v[2*j] - v[2*j+1], v[2*j+1]);
      #pragma unroll
      for (int j = 0; j < 2;  ++j) v[j] = fmaf(p2, v[2*j] - v[2*j+1], v[2*j+1]);
      float s = fmaf(p1, v[0] - v[1], v[1]);
      if (half == 0) hv0[rr] = s; else hv1[rr] = s;
    }
  }

  float tvv[8];
  #pragma unroll
  for (int rr = 0; rr < 8; ++rr)
    tvv[rr] = fmaf(p0v[rr], hv0[rr] - hv1[rr], hv1[rr]);

  #pragma unroll
  for (int off = 32; off; off >>= 1) {
    #pragma unroll
    for (int rr = 0; rr < 8; ++rr) tvv[rr] += __shfl_xor(tvv[rr], off, 64);
  }
  if (lane == 0) {
    #pragma unroll
    for (int rr = 0; rr < 8; ++rr) out[rowblk + wv * 8 + rr] = tvv[rr];
  }
}

extern "C" void kernel_launch(void* const* d_in, const int* in_sizes, int n_in,
                              void* d_out, int out_size, void* d_ws, size_t ws_size,
                              hipStream_t stream) {
  const float* x    = (const float*)d_in[0];
  const float* fsel = (const float*)d_in[1];
  const float* thr  = (const float*)d_in[2];
  const float* lw   = (const float*)d_in[3];
  float* out = (float*)d_out;

  bf16_t* pk = (bf16_t*)d_ws;                 // 8 x 393216 B

  const int B = in_sizes[0] / DD;             // 16384

  node_pack<<<dim3(96), dim3(256), 0, stream>>>(fsel, pk);
  node_fused<<<dim3(B / 64), dim3(512), 0, stream>>>(x, pk, thr, lw, out);
}